// Round 5
// baseline (312.993 us; speedup 1.0000x reference)
//
#include <hip/hip_runtime.h>
#include <hip/hip_bf16.h>

typedef __attribute__((ext_vector_type(8))) short bf16x8;
typedef __attribute__((ext_vector_type(8))) unsigned short u16x8;
typedef __attribute__((ext_vector_type(4))) unsigned short u16x4;
typedef __attribute__((ext_vector_type(4))) float f32x4;
typedef __attribute__((ext_vector_type(4))) int i32x4;

#define NB 4   // 4 x 16 = 64 kv columns per tile

__device__ __forceinline__ unsigned short f2bf(float f) {
    union { __hip_bfloat16 h; unsigned short u; } cv;
    cv.h = __float2bfloat16(f);
    return cv.u;
}

__global__ __launch_bounds__(256, 4) void attn_fwd(
    const float* __restrict__ Vg, const float* __restrict__ Kg,
    const float* __restrict__ Qg, const int* __restrict__ Mg,
    float* __restrict__ Og)
{
    constexpr int S = 2048, H = 16, D = 64, SROW = H * D;
    // softmax scale 1/sqrt(1024) folded with log2(e): work in exp2 space
    constexpr float CST = 0.03125f * 1.44269504088896f;

    // double-buffered K/V tiles + per-wave P scratch: 16+16+8 = 40 KB -> 4 blocks/CU
    __shared__ unsigned short Klds[2][64 * 64];     // [kv][d]  bf16, XOR-swizzled
    __shared__ unsigned short VTlds[2][64 * 64];    // [d][kv]  bf16, XOR-swizzled
    __shared__ unsigned short Plds[4][16 * 64];     // per-wave [q][kv]

    const int tid  = threadIdx.x;
    const int lane = tid & 63;
    const int w    = tid >> 6;
    const int c    = lane & 15;   // fragment col index (= this lane's q-row)
    const int g    = lane >> 4;   // fragment k-group

    // T1: bijective XCD swizzle (2048 blocks, 8 XCDs, 256 per XCD)
    const int logical = (blockIdx.x & 7) * 256 + (blockIdx.x >> 3);
    const int qb  = logical & 31;
    const int h   = (logical >> 5) & 15;
    const int b   = logical >> 9;

    const int q0 = qb * 64 + w * 16;   // 16 q-rows per wave

    const size_t base = ((size_t)b * S * H + h) * D;
    const float* Qp = Qg + base;
    const float* Kp = Kg + base;
    const float* Vp = Vg + base;
    float*       Op = Og + base;
    const int*   Mp = Mg + b * S;

    // staging coords
    const int kr  = tid >> 2;          // K-stage row 0..63
    const int kc0 = (tid & 3) << 4;    // K-stage col {0,16,32,48}
    const int vk  = (tid & 31) << 1;   // V-stage kv row pair base
    const int vd0 = (tid >> 5) << 3;   // V-stage d base {0..56}

    // ---- Q fragments, held in registers for all 32 KV tiles ----
    bf16x8 qf[2];
#pragma unroll
    for (int ks = 0; ks < 2; ++ks) {
        const float* qr = Qp + (size_t)(q0 + c) * SROW + ks * 32 + g * 8;
        f32x4 x = *(const f32x4*)qr;
        f32x4 y = *(const f32x4*)(qr + 4);
        bf16x8 f;
#pragma unroll
        for (int j = 0; j < 4; ++j) { f[j] = (short)f2bf(x[j]); f[4 + j] = (short)f2bf(y[j]); }
        qf[ks] = f;
    }

    f32x4 oacc[NB];
    float m_run = -INFINITY, l_run = 0.0f;   // per-lane: stats for q-row c
#pragma unroll
    for (int nb = 0; nb < NB; ++nb) oacc[nb] = f32x4{0.f, 0.f, 0.f, 0.f};

    // staging registers (live across compute — hides HBM latency under MFMA/softmax)
    f32x4 kstg[4], vstg[4];
    i32x4 mnx[NB];    // mask for kv = 16*nb + 4*g + r

    auto STAGE_LOAD = [&](int t) {
        const int k0 = t * 64;
        const float* src = Kp + (size_t)(k0 + kr) * SROW + kc0;
        kstg[0] = *(const f32x4*)(src);
        kstg[1] = *(const f32x4*)(src + 4);
        kstg[2] = *(const f32x4*)(src + 8);
        kstg[3] = *(const f32x4*)(src + 12);
        const float* s0 = Vp + (size_t)(k0 + vk) * SROW + vd0;
        const float* s1 = s0 + SROW;
        vstg[0] = *(const f32x4*)(s0);
        vstg[1] = *(const f32x4*)(s0 + 4);
        vstg[2] = *(const f32x4*)(s1);
        vstg[3] = *(const f32x4*)(s1 + 4);
#pragma unroll
        for (int nb = 0; nb < NB; ++nb)
            mnx[nb] = *(const i32x4*)&Mp[k0 + nb * 16 + 4 * g];
    };

    auto STAGE_WRITE = [&](int buf) {
        // K tile: two swizzled b128 writes
        u16x8 w0, w1;
#pragma unroll
        for (int j = 0; j < 4; ++j) {
            w0[j]     = f2bf(kstg[0][j]);
            w0[4 + j] = f2bf(kstg[1][j]);
            w1[j]     = f2bf(kstg[2][j]);
            w1[4 + j] = f2bf(kstg[3][j]);
        }
        char* kb = (char*)Klds[buf] + kr * 128;
        *(u16x8*)(kb + ((kc0 * 2)      ^ ((kr & 7) << 4))) = w0;
        *(u16x8*)(kb + ((kc0 * 2 + 16) ^ ((kr & 7) << 4))) = w1;
        // V tile transposed: packed b32 writes
        char* vbase = (char*)VTlds[buf];
#pragma unroll
        for (int j = 0; j < 8; ++j) {
            int d = vd0 + j;
            float lo = (j < 4) ? vstg[0][j] : vstg[1][j - 4];
            float hi = (j < 4) ? vstg[2][j] : vstg[3][j - 4];
            unsigned int val = (unsigned int)f2bf(lo) | ((unsigned int)f2bf(hi) << 16);
            *(unsigned int*)(vbase + d * 128 + ((vk * 2) ^ ((d & 7) << 4))) = val;
        }
    };

    // ---- prologue: stage tile 0 into buffer 0 ----
    STAGE_LOAD(0);
    STAGE_WRITE(0);
    __syncthreads();

    for (int t = 0; t < 32; ++t) {
        const int cur = t & 1;
        const int nxt = cur ^ 1;

        // masks for the current tile (loaded during the previous iteration)
        i32x4 mv[NB];
#pragma unroll
        for (int nb = 0; nb < NB; ++nb) mv[nb] = mnx[nb];

        // issue next tile's global loads NOW; consume after compute (T14)
        if (t < 31) STAGE_LOAD(t + 1);

        // ---- swapped QK^T: S^T = K(16kv x 32d) . Q^T  via mfma(kf, qf) ----
        // lane (c,g) reg r holds S^T[kv=16nb+4g+r][q=c]
        f32x4 sacc[NB];
#pragma unroll
        for (int nb = 0; nb < NB; ++nb) sacc[nb] = f32x4{0.f, 0.f, 0.f, 0.f};

        __builtin_amdgcn_s_setprio(1);
#pragma unroll
        for (int nb = 0; nb < NB; ++nb) {
#pragma unroll
            for (int ksl = 0; ksl < 2; ++ksl) {
                bf16x8 kf = *(const bf16x8*)((char*)Klds[cur] + (nb * 16 + c) * 128 +
                                             ((ksl * 64 + g * 16) ^ ((c & 7) << 4)));
                sacc[nb] = __builtin_amdgcn_mfma_f32_16x16x32_bf16(
                    kf, qf[ksl], sacc[nb], 0, 0, 0);
            }
        }
        __builtin_amdgcn_s_setprio(0);

        // ---- mask + scale into log2 space (per-lane, q-row = c) ----
#pragma unroll
        for (int nb = 0; nb < NB; ++nb)
#pragma unroll
            for (int r = 0; r < 4; ++r)
                sacc[nb][r] = mv[nb][r] ? sacc[nb][r] * CST : -1e20f;

        // ---- online softmax: in-register row reduce + 2-step cross-g shfl ----
        float tmx = fmaxf(fmaxf(fmaxf(sacc[0][0], sacc[0][1]), fmaxf(sacc[0][2], sacc[0][3])),
                          fmaxf(fmaxf(sacc[1][0], sacc[1][1]), fmaxf(sacc[1][2], sacc[1][3])));
        tmx = fmaxf(tmx,
              fmaxf(fmaxf(fmaxf(sacc[2][0], sacc[2][1]), fmaxf(sacc[2][2], sacc[2][3])),
                    fmaxf(fmaxf(sacc[3][0], sacc[3][1]), fmaxf(sacc[3][2], sacc[3][3]))));
        tmx = fmaxf(tmx, __shfl_xor(tmx, 16));
        tmx = fmaxf(tmx, __shfl_xor(tmx, 32));

        float mn = fmaxf(m_run, tmx);
        float alpha_c = __builtin_amdgcn_exp2f(m_run - mn);
        m_run = mn;

        // p = exp2(lg - m)
#pragma unroll
        for (int nb = 0; nb < NB; ++nb)
#pragma unroll
            for (int r = 0; r < 4; ++r)
                sacc[nb][r] = __builtin_amdgcn_exp2f(sacc[nb][r] - m_run);

        // row sum (in-register + 2 shfl) -> running denominator
        float sm = ((sacc[0][0] + sacc[0][1]) + (sacc[0][2] + sacc[0][3]))
                 + ((sacc[1][0] + sacc[1][1]) + (sacc[1][2] + sacc[1][3]))
                 + ((sacc[2][0] + sacc[2][1]) + (sacc[2][2] + sacc[2][3]))
                 + ((sacc[3][0] + sacc[3][1]) + (sacc[3][2] + sacc[3][3]));
        sm += __shfl_xor(sm, 16);
        sm += __shfl_xor(sm, 32);
        l_run = l_run * alpha_c + sm;

        // ---- O rescale: alpha lives at lane q=c, O rows are q=4g+r ----
        float alpha_row[4];
#pragma unroll
        for (int r = 0; r < 4; ++r)
            alpha_row[r] = __shfl(alpha_c, 4 * g + r);
#pragma unroll
        for (int nb = 0; nb < NB; ++nb)
#pragma unroll
            for (int r = 0; r < 4; ++r)
                oacc[nb][r] *= alpha_row[r];

        // ---- write P^T (bf16) to per-wave LDS: row q=c, 4 consecutive kv per b64 ----
        char* pb = (char*)Plds[w];
#pragma unroll
        for (int nb = 0; nb < NB; ++nb) {
            u16x4 pk;
#pragma unroll
            for (int r = 0; r < 4; ++r) pk[r] = f2bf(sacc[nb][r]);
            *(u16x4*)(pb + c * 128 + (((nb * 16 + 4 * g) * 2) ^ ((c & 7) << 4))) = pk;
        }

        // ---- PV: O += P(16x64) . V ----
        bf16x8 pa[2];
#pragma unroll
        for (int ksl = 0; ksl < 2; ++ksl)
            pa[ksl] = *(const bf16x8*)(pb + c * 128 +
                                       ((ksl * 64 + g * 16) ^ ((c & 7) << 4)));
        __builtin_amdgcn_s_setprio(1);
#pragma unroll
        for (int nd = 0; nd < NB; ++nd) {
#pragma unroll
            for (int ksl = 0; ksl < 2; ++ksl) {
                bf16x8 vf = *(const bf16x8*)((char*)VTlds[cur] + (nd * 16 + c) * 128 +
                                             ((ksl * 64 + g * 16) ^ ((c & 7) << 4)));
                oacc[nd] = __builtin_amdgcn_mfma_f32_16x16x32_bf16(
                    pa[ksl], vf, oacc[nd], 0, 0, 0);
            }
        }
        __builtin_amdgcn_s_setprio(0);

        // ---- write next tile's staged data to the other buffer, then one barrier ----
        if (t < 31) STAGE_WRITE(nxt);
        __syncthreads();
    }

    // ---- epilogue: O / l, fp32 store (l lives at lane q=c, O rows are q=4g+r) ----
    float rinv[4];
#pragma unroll
    for (int r = 0; r < 4; ++r) rinv[r] = 1.0f / __shfl(l_run, 4 * g + r);
#pragma unroll
    for (int nd = 0; nd < NB; ++nd)
#pragma unroll
        for (int r = 0; r < 4; ++r) {
            int qrow = q0 + 4 * g + r;
            int dcol = nd * 16 + c;
            Op[(size_t)qrow * SROW + dcol] = oacc[nd][r] * rinv[r];
        }
}

extern "C" void kernel_launch(void* const* d_in, const int* in_sizes, int n_in,
                              void* d_out, int out_size, void* d_ws, size_t ws_size,
                              hipStream_t stream) {
    const float* V = (const float*)d_in[0];
    const float* K = (const float*)d_in[1];
    const float* Q = (const float*)d_in[2];
    const int*   M = (const int*)d_in[3];
    float*       O = (float*)d_out;
    // grid: 32 q-blocks x 16 heads x 4 batch = 2048 blocks, 256 threads
    attn_fwd<<<dim3(2048), dim3(256), 0, stream>>>(V, K, Q, M, O);
}